// Round 1
// baseline (6529.559 us; speedup 1.0000x reference)
//
#include <hip/hip_runtime.h>
#include <cstddef>

#define BB 256
#define SS 1024
#define VV 288
#define EE 100
#define HH 128
#define G4 512
#define TC 16

__device__ __forceinline__ float sigmoid_f(float x) {
    return __fdividef(1.0f, 1.0f + __expf(-x));
}
__device__ __forceinline__ float tanh_f(float x) {
    x = fminf(fmaxf(x, -15.0f), 15.0f);
    float e = __expf(2.0f * x);
    return __fdividef(e - 1.0f, e + 1.0f);
}

// table[v][j] = bih0[j]+bhh0[j] + sum_e emb[v][e] * Wih0[j][e]
__global__ __launch_bounds__(512) void proj_kernel(
    const float* __restrict__ emb, const float* __restrict__ Wih0,
    const float* __restrict__ bih0, const float* __restrict__ bhh0,
    float* __restrict__ table)
{
    __shared__ float er[EE];
    const int v = blockIdx.x;
    const int j = threadIdx.x;
    for (int e = j; e < EE; e += 512) er[e] = emb[v * EE + e];
    __syncthreads();
    float acc = bih0[j] + bhh0[j];
    const float* wr = Wih0 + j * EE;
#pragma unroll 4
    for (int e = 0; e < EE; e++) acc = fmaf(er[e], wr[e], acc);
    table[v * G4 + j] = acc;
}

// Wih [G4][HH] -> WihT [HH][G4]
__global__ __launch_bounds__(256) void transpose_kernel(
    const float* __restrict__ Wih, float* __restrict__ WihT)
{
    const int idx = blockIdx.x * 256 + threadIdx.x;  // G4*HH = 65536 total
    const int jj = idx >> 7;     // row in Wih (0..511)
    const int kk = idx & 127;    // col in Wih (0..127)
    WihT[kk * G4 + jj] = Wih[idx];
}

// Layer 0: one workgroup per batch element. Whh row j in registers of thread j.
__global__ __launch_bounds__(512, 2) void lstm0_kernel(
    const int* __restrict__ text, const float* __restrict__ table,
    const float* __restrict__ Whh, float* __restrict__ hout)
{
    __shared__ float h_lds[HH];
    __shared__ float gact[G4];
    const int b = blockIdx.x;
    const int j = threadIdx.x;
    float w[HH];
    {
        const float4* wsrc = (const float4*)(Whh + (size_t)j * HH);
#pragma unroll
        for (int q = 0; q < 32; q++) {
            float4 t = wsrc[q];
            w[4*q+0] = t.x; w[4*q+1] = t.y; w[4*q+2] = t.z; w[4*q+3] = t.w;
        }
    }
    if (j < HH) h_lds[j] = 0.0f;
    float c = 0.0f;
    const int quarter = j >> 7;
    const int* tptr = text + (size_t)b * SS;
    __syncthreads();
    for (int t = 0; t < SS; t++) {
        const int tok = tptr[t];
        float g = table[(size_t)tok * G4 + j];
        const float4* h4 = (const float4*)h_lds;
#pragma unroll
        for (int q = 0; q < 32; q++) {
            float4 hv = h4[q];
            g = fmaf(hv.x, w[4*q+0], g);
            g = fmaf(hv.y, w[4*q+1], g);
            g = fmaf(hv.z, w[4*q+2], g);
            g = fmaf(hv.w, w[4*q+3], g);
        }
        gact[j] = (quarter == 2) ? tanh_f(g) : sigmoid_f(g);
        __syncthreads();
        if (j < HH) {
            const float gi = gact[j];
            const float gf = gact[j + HH];
            const float gg = gact[j + 2*HH];
            const float go = gact[j + 3*HH];
            c = fmaf(gf, c, gi * gg);
            const float hv = go * tanh_f(c);
            h_lds[j] = hv;
            hout[((size_t)t * BB + b) * HH + j] = hv;
        }
        __syncthreads();
    }
}

// Layers 1,2: in-place on hbuf. Input projection computed just-in-time per
// 16-step chunk with LDS-tiled WihT; recurrence like layer 0.
__global__ __launch_bounds__(512, 2) void lstm12_kernel(
    const float* __restrict__ WihT, const float* __restrict__ Whh,
    const float* __restrict__ bih, const float* __restrict__ bhh,
    float* hbuf)
{
    __shared__ float h_lds[HH];
    __shared__ float gact[G4];
    __shared__ float hin[TC][HH];     // staged inputs (prev layer h), 8 KB
    __shared__ float wtile[TC][G4];   // Wih k-tile; reused as xg chunk, 32 KB
    const int b = blockIdx.x;
    const int j = threadIdx.x;
    float w[HH];
    {
        const float4* wsrc = (const float4*)(Whh + (size_t)j * HH);
#pragma unroll
        for (int q = 0; q < 32; q++) {
            float4 t = wsrc[q];
            w[4*q+0] = t.x; w[4*q+1] = t.y; w[4*q+2] = t.z; w[4*q+3] = t.w;
        }
    }
    const float bj = bih[j] + bhh[j];
    if (j < HH) h_lds[j] = 0.0f;
    float c = 0.0f;
    const int quarter = j >> 7;
    __syncthreads();
    for (int t0 = 0; t0 < SS; t0 += TC) {
        // stage prev-layer h rows t0..t0+15 for this b (read-before-overwrite)
        {
            const int r = j >> 5;
            const int c4 = j & 31;
            const float4 v = ((const float4*)(hbuf + ((size_t)(t0 + r) * BB + b) * HH))[c4];
            ((float4*)&hin[r][0])[c4] = v;
        }
        float acc[TC];
#pragma unroll
        for (int t = 0; t < TC; t++) acc[t] = bj;
        for (int ko = 0; ko < 8; ko++) {
            __syncthreads();   // prev compute done / hin visible
#pragma unroll
            for (int p = 0; p < 4; p++) {
                const int fi = j + p * 512;
                const int r = fi >> 7;
                const int cc = fi & 127;
                ((float4*)&wtile[r][0])[cc] =
                    ((const float4*)(WihT + (size_t)(ko * TC + r) * G4))[cc];
            }
            __syncthreads();
#pragma unroll
            for (int k = 0; k < TC; k++) {
                const float wk = wtile[k][j];
#pragma unroll
                for (int t = 0; t < TC; t++)
                    acc[t] = fmaf(hin[t][ko * TC + k], wk, acc[t]);
            }
        }
        __syncthreads();       // all wtile reads done before reuse as xg
#pragma unroll
        for (int t = 0; t < TC; t++) wtile[t][j] = acc[t];
        for (int tt = 0; tt < TC; tt++) {
            float g = wtile[tt][j];   // own write, no barrier needed
            const float4* h4 = (const float4*)h_lds;
#pragma unroll
            for (int q = 0; q < 32; q++) {
                float4 hv = h4[q];
                g = fmaf(hv.x, w[4*q+0], g);
                g = fmaf(hv.y, w[4*q+1], g);
                g = fmaf(hv.z, w[4*q+2], g);
                g = fmaf(hv.w, w[4*q+3], g);
            }
            gact[j] = (quarter == 2) ? tanh_f(g) : sigmoid_f(g);
            __syncthreads();
            if (j < HH) {
                const float gi = gact[j];
                const float gf = gact[j + HH];
                const float gg = gact[j + 2*HH];
                const float go = gact[j + 3*HH];
                c = fmaf(gf, c, gi * gg);
                const float hv = go * tanh_f(c);
                h_lds[j] = hv;
                hbuf[((size_t)(t0 + tt) * BB + b) * HH + j] = hv;
            }
            __syncthreads();
        }
    }
}

// FC head: out[m][n] = dot(h[m], fcW[n]) + fcb[n]; M=262144, N=288, K=128
__global__ __launch_bounds__(256) void fc_kernel(
    const float* __restrict__ hbuf, const float* __restrict__ fcW,
    const float* __restrict__ fcb, float* __restrict__ out)
{
    __shared__ float Ash[128][68];    // A^T tile, padded (272 B rows, 16B-aligned)
    __shared__ float Bsh[32][132];    // B tile natural, padded (528 B rows)
    const int tid = threadIdx.x;
    const size_t mb = (size_t)blockIdx.x * 64;
    const int nb = blockIdx.y * 32;
#pragma unroll
    for (int p = 0; p < 8; p++) {
        const int fi = tid + p * 256;
        const int m = fi >> 5, k4 = fi & 31;
        float4 v = ((const float4*)(hbuf + (mb + m) * HH))[k4];
        Ash[k4*4+0][m] = v.x;
        Ash[k4*4+1][m] = v.y;
        Ash[k4*4+2][m] = v.z;
        Ash[k4*4+3][m] = v.w;
    }
#pragma unroll
    for (int p = 0; p < 4; p++) {
        const int fi = tid + p * 256;
        const int n = fi >> 5, k4 = fi & 31;
        ((float4*)&Bsh[n][0])[k4] = ((const float4*)(fcW + (size_t)(nb + n) * HH))[k4];
    }
    __syncthreads();
    const int tni = tid & 15, tmi = tid >> 4;
    const int m0 = tmi * 4, n0 = tni * 2;
    float a00=0,a01=0,a10=0,a11=0,a20=0,a21=0,a30=0,a31=0;
#pragma unroll 8
    for (int k = 0; k < 128; k++) {
        const float4 av = *((const float4*)&Ash[k][m0]);
        const float b0v = Bsh[n0][k], b1v = Bsh[n0+1][k];
        a00 = fmaf(av.x, b0v, a00); a01 = fmaf(av.x, b1v, a01);
        a10 = fmaf(av.y, b0v, a10); a11 = fmaf(av.y, b1v, a11);
        a20 = fmaf(av.z, b0v, a20); a21 = fmaf(av.z, b1v, a21);
        a30 = fmaf(av.w, b0v, a30); a31 = fmaf(av.w, b1v, a31);
    }
    const float c0 = fcb[nb + n0], c1 = fcb[nb + n0 + 1];
    float* o0 = out + (mb + m0 + 0) * VV + nb + n0;
    float* o1 = out + (mb + m0 + 1) * VV + nb + n0;
    float* o2 = out + (mb + m0 + 2) * VV + nb + n0;
    float* o3 = out + (mb + m0 + 3) * VV + nb + n0;
    *((float2*)o0) = make_float2(a00 + c0, a01 + c1);
    *((float2*)o1) = make_float2(a10 + c0, a11 + c1);
    *((float2*)o2) = make_float2(a20 + c0, a21 + c1);
    *((float2*)o3) = make_float2(a30 + c0, a31 + c1);
}

extern "C" void kernel_launch(void* const* d_in, const int* in_sizes, int n_in,
                              void* d_out, int out_size, void* d_ws, size_t ws_size,
                              hipStream_t stream)
{
    (void)in_sizes; (void)n_in; (void)out_size; (void)ws_size;
    const int*   text = (const int*)  d_in[0];
    const float* emb  = (const float*)d_in[1];
    const float* fcW  = (const float*)d_in[2];
    const float* fcb  = (const float*)d_in[3];
    const float* Wih0 = (const float*)d_in[4];
    const float* Whh0 = (const float*)d_in[5];
    const float* bih0 = (const float*)d_in[6];
    const float* bhh0 = (const float*)d_in[7];
    const float* Wih1 = (const float*)d_in[8];
    const float* Whh1 = (const float*)d_in[9];
    const float* bih1 = (const float*)d_in[10];
    const float* bhh1 = (const float*)d_in[11];
    const float* Wih2 = (const float*)d_in[12];
    const float* Whh2 = (const float*)d_in[13];
    const float* bih2 = (const float*)d_in[14];
    const float* bhh2 = (const float*)d_in[15];
    float* out = (float*)d_out;
    float* ws  = (float*)d_ws;

    float* table = ws;                    // 288*512
    float* T1    = table + VV * G4;       // 128*512
    float* T2    = T1 + HH * G4;          // 128*512
    float* hbuf  = T2 + HH * G4;          // 1024*256*128 (reused in place per layer)

    proj_kernel<<<VV, 512, 0, stream>>>(emb, Wih0, bih0, bhh0, table);
    transpose_kernel<<<256, 256, 0, stream>>>(Wih1, T1);
    transpose_kernel<<<256, 256, 0, stream>>>(Wih2, T2);
    lstm0_kernel<<<BB, 512, 0, stream>>>(text, table, Whh0, hbuf);
    lstm12_kernel<<<BB, 512, 0, stream>>>(T1, Whh1, bih1, bhh1, hbuf);
    lstm12_kernel<<<BB, 512, 0, stream>>>(T2, Whh2, bih2, bhh2, hbuf);
    fc_kernel<<<dim3(4096, 9), 256, 0, stream>>>(hbuf, fcW, fcb, out);
}